// Round 1
// baseline (924.946 us; speedup 1.0000x reference)
//
#include <hip/hip_runtime.h>

// LSTM feedback net: B=16384, T=48 warmup, F=4, UNITS=256, 24 AR steps.
// R12 = R11 restructured for 2 blocks/CU (phase overlap across blocks):
//  - 32 batch rows/block, grid 512 -> 2 co-resident blocks per CU whose
//    GEMM (MFMA) and gate (VALU/trans) phases interleave instead of the
//    single-block lockstep [GEMM][barrier][gates] serialization.
//  - register diet to fit 4 waves/SIMD (<=128 total regs, launch_bounds
//    (512,4)): acc 128->64 AGPR (single m-tile), aw ring 3->1 (16 VGPR;
//    per-tile vmcnt stall is hidden by the other 3 waves/SIMD), hb ring 2,
//    c 16. Cross-barrier prestage of next step's tile 0 retained (issued
//    after stage 16, flies over gates + LDS-only barrier).
//  - LDS 37,888 B/block (2 buffers x 32 rows x PITCH) -> 75,776 B/CU.
// Numerics identical to R11 (same frags, same gate math, same layouts).

typedef unsigned short u16;
typedef __attribute__((ext_vector_type(8))) short bf16x8;
typedef __attribute__((ext_vector_type(4))) float f32x4;
typedef __attribute__((ext_vector_type(16))) float f32x16;

#define PITCH 296    // hext row pitch, elems (592 B/row)
#define HB 9472      // elems per h buffer (32*296)
#define WARM 48
#define STEPS 71     // 48 warmup + 23 AR cell steps
#define LOG2E  1.442695041f
#define LOG2E2 2.885390082f

__device__ __forceinline__ u16 f2bf(float f) {
    unsigned u = __float_as_uint(f);
    u += 0x7FFFu + ((u >> 16) & 1u);   // round-to-nearest-even
    return (u16)(u >> 16);
}

// pack 2 f32 -> 2 bf16 (RNE), one VOP3 instr
__device__ __forceinline__ unsigned pk_bf16(float a, float b) {
    unsigned d;
    asm("v_cvt_pk_bf16_f32 %0, %1, %2" : "=v"(d) : "v"(a), "v"(b));
    return d;
}

// LDS-only barrier: drain LDS ops, NOT vmcnt -> global loads stay in flight.
__device__ __forceinline__ void sync_lds() {
    asm volatile("s_waitcnt lgkmcnt(0)\n\ts_barrier" ::: "memory");
}

// ---- prep: 32x32x16 A-fragments of W' (K=272 x N=1024), 17 kt tiles.
// Frag order: idx = kt*32 + wv*4 + g  (g fastest -> imm-offset loads).
// Lane l of a frag holds W'[kt*16+(l>>5)*8+j][256g+32wv+(l&31)], j=0..7.
// K rows: 0..255 Wh, 256..259 Wx, 260 bias. Cols scaled log2e / 2log2e (g).
// wd16: 9 K32-chunks of Wd^T in 16x16x32 A-layout (m=feature), unscaled.
__global__ void prep_weights(const float* __restrict__ Wx,
                             const float* __restrict__ Wh,
                             const float* __restrict__ b,
                             const float* __restrict__ Wd,
                             const float* __restrict__ bd,
                             u16* __restrict__ whext,
                             u16* __restrict__ wdp) {
    int idx = blockIdx.x * 256 + threadIdx.x;   // one thread per 16B chunk
    if (idx < 34816) {                          // 17 kt * 8 wv * 4 g * 64 lanes
        int lane = idx & 63;
        int fr = idx >> 6;
        int g = fr & 3;
        int wv = (fr >> 2) & 7;
        int kt = fr >> 5;
        int k0 = kt * 16 + (lane >> 5) * 8;
        int n = 256 * g + 32 * wv + (lane & 31);
        float sc = (g == 2) ? LOG2E2 : LOG2E;
        u16 v[8];
#pragma unroll
        for (int j = 0; j < 8; ++j) {
            int k = k0 + j;
            float f = 0.0f;
            if (k < 256) f = Wh[k * 1024 + n];
            else if (k < 260) f = Wx[(k - 256) * 1024 + n];
            else if (k == 260) f = b[n];
            v[j] = f2bf(f * sc);
        }
        ushort4* dst = (ushort4*)(whext + (size_t)idx * 8);
        dst[0] = make_ushort4(v[0], v[1], v[2], v[3]);
        dst[1] = make_ushort4(v[4], v[5], v[6], v[7]);
    } else if (idx < 34816 + 576) {             // wd16: 9 chunks x 64 lanes
        int id2 = idx - 34816;
        int lane = id2 & 63;
        int kc = id2 >> 6;
        int m = lane & 15;                      // feature row
        int k0 = kc * 32 + (lane >> 4) * 8;
        u16 v[8];
#pragma unroll
        for (int j = 0; j < 8; ++j) {
            int k = k0 + j;
            float f = 0.0f;
            if (m < 4) {
                if (k < 256) f = Wd[k * 4 + m];
                else if (k == 260) f = bd[m];
            }
            v[j] = f2bf(f);
        }
        ushort4* dst = (ushort4*)(wdp + (size_t)id2 * 8);
        dst[0] = make_ushort4(v[0], v[1], v[2], v[3]);
        dst[1] = make_ushort4(v[4], v[5], v[6], v[7]);
    }
}

// wave base wpw = whext + w*4096B; per kt stride 32768B; per g imm 1024B.
#define WL(DST, T) do {                                                       \
    const char* _p = wpw + ((size_t)(T) << 15);                               \
    DST[0] = *(const bf16x8*)(_p + voffl);                                    \
    DST[1] = *(const bf16x8*)(_p + voffl + 1024);                             \
    DST[2] = *(const bf16x8*)(_p + voffl + 2048);                             \
    DST[3] = *(const bf16x8*)(_p + voffl + 3072);                             \
} while (0)

#define HL1(DST, T) do { DST = *(const bf16x8*)&hr[hrow + (T) * 16]; } while (0)

#define MT1(HBX)                                                              \
    _Pragma("unroll") for (int g = 0; g < 4; ++g)                             \
        acc[g] = __builtin_amdgcn_mfma_f32_32x32x16_bf16(                     \
            aw[g], HBX, acc[g], 0, 0, 0);

// one ring-1 stage: consume tile K from (aw, HBX), refill aw<-K+1, HBX<-K+2
#define STG1(K, HBX) do { MT1(HBX); WL(aw, (K) + 1); HL1(HBX, (K) + 2); } while (0)

__global__ __launch_bounds__(512, 4) void lstm_main(
    const float* __restrict__ x, const u16* __restrict__ whext,
    const u16* __restrict__ wdp, float* __restrict__ out) {
    __shared__ __align__(16) u16 hbuf[2 * HB];   // h double buffer, 37,888 B

    const int tid = threadIdx.x;
    const int w = tid >> 6;        // wave 0..7 -> units [32w, 32w+32)
    const int l = tid & 63;
    const int l31 = l & 31;
    const int lh = l >> 5;
    const long long rowBase = (long long)blockIdx.x * 32;

    {   // zero both h buffers (incl. pad cols 261..287 -- stay zero forever)
        int4 z = make_int4(0, 0, 0, 0);
        for (int i = tid; i < 2368; i += 512) ((int4*)hbuf)[i] = z;
    }
    sync_lds();
    if (tid < 32) {
        hbuf[tid * PITCH + 260] = (u16)0x3F80;        // bias-1 col, buffer 0
        hbuf[HB + tid * PITCH + 260] = (u16)0x3F80;   // and buffer 1
        const float4 xv = *(const float4*)(x + (rowBase + tid) * 192);
        uint2* p = (uint2*)&hbuf[tid * PITCH + 256];   // x_0 -> buffer 0
        *p = make_uint2(pk_bf16(xv.x, xv.y), pk_bf16(xv.z, xv.w));
    }

    const char* __restrict__ wpw = (const char*)whext + (size_t)w * 4096;
    const char* __restrict__ dp = (const char*)wdp;
    const int voffl = l * 16;
    const int hrow = l31 * PITCH + lh * 8;           // B-frag row (elems)

    f32x16 c = {};         // cell state: batch l31; reg r -> unit
                           // 32w + (r&3) + 8*(r>>2) + 4*lh
    bf16x8 aw[4];          // ring-1 weight frags (one kt tile, 4 gates)
    WL(aw, 0);             // in flight across the first barrier

    for (int step = 0; step < STEPS; ++step) {
        const u16* hr = hbuf + (step & 1) * HB;      // read buffer
        u16* hw = hbuf + ((step & 1) ^ 1) * HB;      // write buffer

        // wave 0: issue next warmup x load now; used ~1 step later at step end
        float4 xv = make_float4(0.f, 0.f, 0.f, 0.f);
        if (w == 0 && l < 32 && step < WARM - 1)
            xv = *(const float4*)(x + (rowBase + l) * 192 + (step + 1) * 4);

        sync_lds();   // hr ready; prior reads of hw done; aw (tile 0) in flight

        f32x16 acc[4] = {};      // [gate]
        bf16x8 hb0, hb1;         // 2-ring: tile k lives in hb(k&1)
        HL1(hb0, 0);
        HL1(hb1, 1);

        // 17 K-tiles, ring-1 aw. Stage k: MT(aw, hb[k&1]); aw<-k+1; hb<-k+2.
#pragma unroll 1
        for (int k = 0; k < 14; k += 2) {
            STG1(k, hb0);
            STG1(k + 1, hb1);
        }
        MT1(hb0); WL(aw, 15); HL1(hb0, 16);   // tile 14
        MT1(hb1); WL(aw, 16);                 // tile 15
        MT1(hb0); WL(aw, 0);                  // tile 16; prestage NEXT step's 0
        // aw now holds next step's tile 0, flying over gates + barrier

        // gates; lane holds batch l31, units 32w + (r&3)+8*(r>>2)+4*lh.
        // 7 transcendentals/elem: 5 exp2 + 2 rcp.
        {
            const int hwrow = l31 * PITCH + 32 * w + 4 * lh;
#pragma unroll
            for (int q = 0; q < 4; ++q) {
                unsigned pk[2];
#pragma unroll
                for (int hp = 0; hp < 2; ++hp) {
                    float h2[2];
#pragma unroll
                    for (int rr = 0; rr < 2; ++rr) {
                        const int r = q * 4 + hp * 2 + rr;
                        float ei = __builtin_amdgcn_exp2f(-acc[0][r]);
                        float ef = __builtin_amdgcn_exp2f(-acc[1][r]);
                        float eg = __builtin_amdgcn_exp2f(-acc[2][r]);
                        float eo = __builtin_amdgcn_exp2f(-acc[3][r]);
                        float ai = 1.0f + ei, af = 1.0f + ef;
                        float ag = 1.0f + eg, ao = 1.0f + eo;
                        float P  = ai * ag;
                        float rD = __builtin_amdgcn_rcpf(P * af);
                        float cn = fmaf(c[r] * P, rD, (1.0f - eg) * af * rD);
                        c[r] = cn;
                        float ec = __builtin_amdgcn_exp2f(-LOG2E2 * cn);
                        float rE = __builtin_amdgcn_rcpf(ao * (1.0f + ec));
                        h2[rr] = (1.0f - ec) * rE;
                    }
                    pk[hp] = pk_bf16(h2[0], h2[1]);
                }
                *(uint2*)&hw[hwrow + 8 * q] = make_uint2(pk[0], pk[1]);
            }
        }

        if (step < WARM - 1) {
            if (w == 0 && l < 32) {   // x_{step+1} (prefetched at step top) -> hw
                uint2* p = (uint2*)&hw[l * PITCH + 256];
                *p = make_uint2(pk_bf16(xv.x, xv.y), pk_bf16(xv.z, xv.w));
            }
        } else {
            sync_lds();        // h_new in hw visible for pred GEMM
            if (w < 2) {       // pred on 2 waves, 16x16x32: batch-tile-16 = w
                f32x4 pacc = {};
                const int col = l & 15;                     // batch within tile
                const int prow = (16 * w + col) * PITCH + (l >> 4) * 8;
#pragma unroll
                for (int kc = 0; kc < 9; ++kc) {            // K32 chunks 0..8
                    bf16x8 hbp = *(const bf16x8*)&hw[prow + kc * 32];
                    bf16x8 wap = *(const bf16x8*)(dp + ((size_t)kc * 64 + l) * 16);
                    pacc = __builtin_amdgcn_mfma_f32_16x16x32_bf16(wap, hbp, pacc, 0, 0, 0);
                }
                if ((l >> 4) == 0) {   // quad 0: regs 0..3 = features 0..3
                    int s = step - (WARM - 1);
                    int batch = 16 * w + col;
                    *(float4*)&out[((rowBase + batch) * 24 + s) * 4] =
                        make_float4(pacc[0], pacc[1], pacc[2], pacc[3]);
                    *(uint2*)&hw[batch * PITCH + 256] =   // feed back as next x_t
                        make_uint2(pk_bf16(pacc[0], pacc[1]), pk_bf16(pacc[2], pacc[3]));
                }
            }
        }
    }
}

extern "C" void kernel_launch(void* const* d_in, const int* in_sizes, int n_in,
                              void* d_out, int out_size, void* d_ws, size_t ws_size,
                              hipStream_t stream) {
    const float* x  = (const float*)d_in[0];   // [16384,48,4]
    const float* Wx = (const float*)d_in[1];   // [4,1024]
    const float* Wh = (const float*)d_in[2];   // [256,1024]
    const float* b  = (const float*)d_in[3];   // [1024]
    const float* Wd = (const float*)d_in[4];   // [256,4]
    const float* bd = (const float*)d_in[5];   // [4]
    float* out = (float*)d_out;                // [16384,24,4] fp32

    u16* whext = (u16*)d_ws;                        // 17*32*64*16 = 557056 B
    u16* wdp = (u16*)((char*)d_ws + 557056);        // 9216 B

    prep_weights<<<(34816 + 576 + 255) / 256, 256, 0, stream>>>(Wx, Wh, b, Wd, bd, whext, wdp);
    lstm_main<<<512, 512, 0, stream>>>(x, whext, wdp, out);
}

// Round 2
// 788.789 us; speedup vs baseline: 1.1726x; 1.1726x over previous
//
#include <hip/hip_runtime.h>

// LSTM feedback net: B=16384, T=48 warmup, F=4, UNITS=256, 24 AR steps.
// R13 = R11 (64 rows/block, 256 blocks, 2 waves/SIMD) + stream-under-gates:
//  - R12 post-mortem: GEMM phase is weight-STREAM-bound (557KB/CU/step
//    through the CU load port); 2 blocks/CU doubled the stream -> slower.
//    So: keep 1 block/CU and instead keep the port busy during gates.
//  - c state moved to LDS (64KB, per-thread f32x4 chunks, coalesced
//    tid*16B -> no cross-thread sync needed). Frees 32 VGPR.
//  - aw ring 3 -> 5 with freed regs: 5 tiles (20KB/wave, 160KB/CU) in
//    flight across the gates phase + LDS-only barrier, and 5-deep
//    pipelining inside the GEMM phase. ~29% of stream hidden under gates.
// Invariant: acc 128 (AGPR) + VGPR (aw80 + hb16 + misc~32) <= 256 -> no spill.
// LDS: hbuf 75,776 + cbuf 65,536 = 141,312 B (<160K, 1 block/CU).

typedef unsigned short u16;
typedef __attribute__((ext_vector_type(8))) short bf16x8;
typedef __attribute__((ext_vector_type(4))) float f32x4;
typedef __attribute__((ext_vector_type(16))) float f32x16;

#define PITCH 296    // hext row pitch, elems (592 B/row)
#define HB 18944     // elems per h buffer (64*296)
#define WARM 48
#define STEPS 71     // 48 warmup + 23 AR cell steps
#define LOG2E  1.442695041f
#define LOG2E2 2.885390082f

__device__ __forceinline__ u16 f2bf(float f) {
    unsigned u = __float_as_uint(f);
    u += 0x7FFFu + ((u >> 16) & 1u);   // round-to-nearest-even
    return (u16)(u >> 16);
}

// pack 2 f32 -> 2 bf16 (RNE), one VOP3 instr
__device__ __forceinline__ unsigned pk_bf16(float a, float b) {
    unsigned d;
    asm("v_cvt_pk_bf16_f32 %0, %1, %2" : "=v"(d) : "v"(a), "v"(b));
    return d;
}

// LDS-only barrier: drain LDS ops, NOT vmcnt -> global loads stay in flight.
__device__ __forceinline__ void sync_lds() {
    asm volatile("s_waitcnt lgkmcnt(0)\n\ts_barrier" ::: "memory");
}

// ---- prep: 32x32x16 A-fragments of W' (K=272 x N=1024), 17 kt tiles.
// Frag order: idx = kt*32 + wv*4 + g  (g fastest -> imm-offset loads).
// Lane l of a frag holds W'[kt*16+(l>>5)*8+j][256g+32wv+(l&31)], j=0..7.
// K rows: 0..255 Wh, 256..259 Wx, 260 bias. Cols scaled log2e / 2log2e (g).
// wd16: 9 K32-chunks of Wd^T in 16x16x32 A-layout (m=feature), unscaled.
__global__ void prep_weights(const float* __restrict__ Wx,
                             const float* __restrict__ Wh,
                             const float* __restrict__ b,
                             const float* __restrict__ Wd,
                             const float* __restrict__ bd,
                             u16* __restrict__ whext,
                             u16* __restrict__ wdp) {
    int idx = blockIdx.x * 256 + threadIdx.x;   // one thread per 16B chunk
    if (idx < 34816) {                          // 17 kt * 8 wv * 4 g * 64 lanes
        int lane = idx & 63;
        int fr = idx >> 6;
        int g = fr & 3;
        int wv = (fr >> 2) & 7;
        int kt = fr >> 5;
        int k0 = kt * 16 + (lane >> 5) * 8;
        int n = 256 * g + 32 * wv + (lane & 31);
        float sc = (g == 2) ? LOG2E2 : LOG2E;
        u16 v[8];
#pragma unroll
        for (int j = 0; j < 8; ++j) {
            int k = k0 + j;
            float f = 0.0f;
            if (k < 256) f = Wh[k * 1024 + n];
            else if (k < 260) f = Wx[(k - 256) * 1024 + n];
            else if (k == 260) f = b[n];
            v[j] = f2bf(f * sc);
        }
        ushort4* dst = (ushort4*)(whext + (size_t)idx * 8);
        dst[0] = make_ushort4(v[0], v[1], v[2], v[3]);
        dst[1] = make_ushort4(v[4], v[5], v[6], v[7]);
    } else if (idx < 34816 + 576) {             // wd16: 9 chunks x 64 lanes
        int id2 = idx - 34816;
        int lane = id2 & 63;
        int kc = id2 >> 6;
        int m = lane & 15;                      // feature row
        int k0 = kc * 32 + (lane >> 4) * 8;
        u16 v[8];
#pragma unroll
        for (int j = 0; j < 8; ++j) {
            int k = k0 + j;
            float f = 0.0f;
            if (m < 4) {
                if (k < 256) f = Wd[k * 4 + m];
                else if (k == 260) f = bd[m];
            }
            v[j] = f2bf(f);
        }
        ushort4* dst = (ushort4*)(wdp + (size_t)id2 * 8);
        dst[0] = make_ushort4(v[0], v[1], v[2], v[3]);
        dst[1] = make_ushort4(v[4], v[5], v[6], v[7]);
    }
}

// wave base wpw = whext + w*4096B; per kt stride 32768B; per g imm 1024B.
#define WL(DST, T) do {                                                       \
    const char* _p = wpw + ((size_t)(T) << 15);                               \
    DST[0] = *(const bf16x8*)(_p + voffl);                                    \
    DST[1] = *(const bf16x8*)(_p + voffl + 1024);                             \
    DST[2] = *(const bf16x8*)(_p + voffl + 2048);                             \
    DST[3] = *(const bf16x8*)(_p + voffl + 3072);                             \
} while (0)

#define HL(DST, T) do {                                                       \
    DST[0] = *(const bf16x8*)&hr[hrow0 + (T) * 16];                           \
    DST[1] = *(const bf16x8*)&hr[hrow1 + (T) * 16];                           \
} while (0)

#define MT(WA, HBX)                                                           \
    _Pragma("unroll") for (int m = 0; m < 2; ++m)                             \
    _Pragma("unroll") for (int g = 0; g < 4; ++g)                             \
        acc[m][g] = __builtin_amdgcn_mfma_f32_32x32x16_bf16(                  \
            WA[g], HBX[m], acc[m][g], 0, 0, 0);

// one pipeline stage: consume tile K from (AW,HBX), refill AW<-K+5, HBX<-K+2
#define STG(K, AW, HBX) do { MT(AW, HBX); WL(AW, (K) + 5); HL(HBX, (K) + 2); } while (0)

__global__ __launch_bounds__(512, 2) void lstm_main(
    const float* __restrict__ x, const u16* __restrict__ whext,
    const u16* __restrict__ wdp, float* __restrict__ out) {
    __shared__ __align__(16) u16 hbuf[2 * HB];     // h double buffer, 75,776 B
    __shared__ __align__(16) float cbuf[16384];    // cell state, 65,536 B
    // cbuf layout: chunk (m*4+q) in cbuf[chunk*2048 + tid*4 .. +3]
    // -> per-thread f32x4, lane-contiguous 16B (coalesced, conflict-free)

    const int tid = threadIdx.x;
    const int w = tid >> 6;        // wave 0..7 -> units [32w, 32w+32)
    const int l = tid & 63;
    const int l31 = l & 31;
    const int lh = l >> 5;
    const long long rowBase = (long long)blockIdx.x * 64;

    {   // zero h buffers (incl. pad cols 261..287) and cell state
        int4 z = make_int4(0, 0, 0, 0);
        for (int i = tid; i < 4736; i += 512) ((int4*)hbuf)[i] = z;
        for (int i = tid; i < 4096; i += 512) ((int4*)cbuf)[i] = z;
    }
    sync_lds();
    if (tid < 64) {
        hbuf[tid * PITCH + 260] = (u16)0x3F80;        // bias-1 col, buffer 0
        hbuf[HB + tid * PITCH + 260] = (u16)0x3F80;   // and buffer 1
        const float4 xv = *(const float4*)(x + (rowBase + tid) * 192);
        uint2* p = (uint2*)&hbuf[tid * PITCH + 256];   // x_0 -> buffer 0
        *p = make_uint2(pk_bf16(xv.x, xv.y), pk_bf16(xv.z, xv.w));
    }

    const char* __restrict__ wpw = (const char*)whext + (size_t)w * 4096;
    const char* __restrict__ dp = (const char*)wdp;
    const int voffl = l * 16;
    const int hrow0 = l31 * PITCH + lh * 8;          // B-frag row, m=0 (elems)
    const int hrow1 = (32 + l31) * PITCH + lh * 8;   // m=1

    bf16x8 aw0[4], aw1[4], aw2[4], aw3[4], aw4[4];   // 5-ring: tile k in aw[k%5]
    WL(aw0, 0);            // all 5 in flight across the first barrier
    WL(aw1, 1);
    WL(aw2, 2);
    WL(aw3, 3);
    WL(aw4, 4);

    for (int step = 0; step < STEPS; ++step) {
        const u16* hr = hbuf + (step & 1) * HB;      // read buffer
        u16* hw = hbuf + ((step & 1) ^ 1) * HB;      // write buffer

        // wave 0: issue next warmup x load now; used ~10us later at step end
        float4 xv = make_float4(0.f, 0.f, 0.f, 0.f);
        if (w == 0 && step < WARM - 1)
            xv = *(const float4*)(x + (rowBase + l) * 192 + (step + 1) * 4);

        sync_lds();   // hr ready; prior reads of hw done; aw0..4 in flight

        f32x16 acc[2][4] = {};   // [batch-tile m][gate]
        bf16x8 hb0[2], hb1[2];   // 2-ring: tile k lives in hb[k&1]
        HL(hb0, 0);
        HL(hb1, 1);

        // 17 K-tiles, ring-5 aw / ring-2 hb. Stage k: MT; WL<-k+5; HL<-k+2.
        STG(0, aw0, hb0);
        STG(1, aw1, hb1);
        STG(2, aw2, hb0);
        STG(3, aw3, hb1);
        STG(4, aw4, hb0);
        STG(5, aw0, hb1);
        STG(6, aw1, hb0);
        STG(7, aw2, hb1);
        STG(8, aw3, hb0);
        STG(9, aw4, hb1);
        STG(10, aw0, hb0);                          // WL <- 15
        STG(11, aw1, hb1);                          // WL <- 16
        MT(aw2, hb0); WL(aw2, 2); HL(hb0, 14);      // tile 12; prestage next-2
        MT(aw3, hb1); WL(aw3, 3); HL(hb1, 15);      // tile 13; prestage next-3
        MT(aw4, hb0); WL(aw4, 4); HL(hb0, 16);      // tile 14; prestage next-4
        MT(aw0, hb1); WL(aw0, 0);                   // tile 15; prestage next-0
        MT(aw1, hb0); WL(aw1, 1);                   // tile 16; prestage next-1
        // aw0..4 now hold NEXT step's tiles 0..4, flying over gates+barrier:
        // 20KB/wave (160KB/CU) streams through the port while VALU does gates.

        // gates; lane holds batch 32m+l31, units 32w + (r&3)+8*(r>>2)+4*lh.
        // 7 transcendentals/elem: 5 exp2 + 2 rcp. c lives in LDS (cbuf).
#pragma unroll
        for (int m = 0; m < 2; ++m) {
            const int hwrow = (32 * m + l31) * PITCH + 32 * w + 4 * lh;
#pragma unroll
            for (int q = 0; q < 4; ++q) {
                float* cp = cbuf + ((m * 4 + q) << 11) + (tid << 2);
                f32x4 cv = *(const f32x4*)cp;
                f32x4 nv;
                unsigned pk[2];
#pragma unroll
                for (int hp = 0; hp < 2; ++hp) {
                    float h2[2];
#pragma unroll
                    for (int rr = 0; rr < 2; ++rr) {
                        const int r = q * 4 + hp * 2 + rr;
                        const int rc = hp * 2 + rr;
                        float ei = __builtin_amdgcn_exp2f(-acc[m][0][r]);
                        float ef = __builtin_amdgcn_exp2f(-acc[m][1][r]);
                        float eg = __builtin_amdgcn_exp2f(-acc[m][2][r]);
                        float eo = __builtin_amdgcn_exp2f(-acc[m][3][r]);
                        float ai = 1.0f + ei, af = 1.0f + ef;
                        float ag = 1.0f + eg, ao = 1.0f + eo;
                        float P  = ai * ag;
                        float rD = __builtin_amdgcn_rcpf(P * af);
                        float cn = fmaf(cv[rc] * P, rD, (1.0f - eg) * af * rD);
                        nv[rc] = cn;
                        float ec = __builtin_amdgcn_exp2f(-LOG2E2 * cn);
                        float rE = __builtin_amdgcn_rcpf(ao * (1.0f + ec));
                        h2[rr] = (1.0f - ec) * rE;
                    }
                    pk[hp] = pk_bf16(h2[0], h2[1]);
                }
                *(f32x4*)cp = nv;
                *(uint2*)&hw[hwrow + 8 * q] = make_uint2(pk[0], pk[1]);
            }
        }

        if (step < WARM - 1) {
            if (w == 0) {   // x_{step+1} (prefetched at step top) -> hw
                uint2* p = (uint2*)&hw[l * PITCH + 256];
                *p = make_uint2(pk_bf16(xv.x, xv.y), pk_bf16(xv.z, xv.w));
            }
        } else {
            sync_lds();        // h_new in hw visible for pred GEMM
            if (w < 4) {       // pred on 4 waves, 16x16x32: batch-tile-16 = w
                f32x4 pacc = {};
                const int col = l & 15;                     // batch within tile
                const int prow = (16 * w + col) * PITCH + (l >> 4) * 8;
#pragma unroll
                for (int kc = 0; kc < 9; ++kc) {            // K32 chunks 0..8
                    bf16x8 hbp = *(const bf16x8*)&hw[prow + kc * 32];
                    bf16x8 wap = *(const bf16x8*)(dp + ((size_t)kc * 64 + l) * 16);
                    pacc = __builtin_amdgcn_mfma_f32_16x16x32_bf16(wap, hbp, pacc, 0, 0, 0);
                }
                if ((l >> 4) == 0) {   // quad 0: regs 0..3 = features 0..3
                    int s = step - (WARM - 1);
                    int batch = 16 * w + col;
                    *(float4*)&out[((rowBase + batch) * 24 + s) * 4] =
                        make_float4(pacc[0], pacc[1], pacc[2], pacc[3]);
                    *(uint2*)&hw[batch * PITCH + 256] =   // feed back as next x_t
                        make_uint2(pk_bf16(pacc[0], pacc[1]), pk_bf16(pacc[2], pacc[3]));
                }
            }
        }
    }
}

extern "C" void kernel_launch(void* const* d_in, const int* in_sizes, int n_in,
                              void* d_out, int out_size, void* d_ws, size_t ws_size,
                              hipStream_t stream) {
    const float* x  = (const float*)d_in[0];   // [16384,48,4]
    const float* Wx = (const float*)d_in[1];   // [4,1024]
    const float* Wh = (const float*)d_in[2];   // [256,1024]
    const float* b  = (const float*)d_in[3];   // [1024]
    const float* Wd = (const float*)d_in[4];   // [256,4]
    const float* bd = (const float*)d_in[5];   // [4]
    float* out = (float*)d_out;                // [16384,24,4] fp32

    u16* whext = (u16*)d_ws;                        // 17*32*64*16 = 557056 B
    u16* wdp = (u16*)((char*)d_ws + 557056);        // 9216 B

    prep_weights<<<(34816 + 576 + 255) / 256, 256, 0, stream>>>(Wx, Wh, b, Wd, bd, whext, wdp);
    lstm_main<<<256, 512, 0, stream>>>(x, whext, wdp, out);
}